// Round 3
// baseline (88.052 us; speedup 1.0000x reference)
//
#include <hip/hip_runtime.h>

// Pixel-shuffle r=4: out[b, c, 4h+i, 4w+j] = in[b, c*16 + i*4 + j, h, w]
// B=32, c_out=25, H=W=64, fp32. Memory-bound permute (420 MB total traffic).
//
// Block (256 thr) loops over 4 tiles; tile = (b, c, h4): 16 ch x 4 rows x 64 w.
// The transpose is WAVE-LOCAL (wave w writes ch 4w..4w+3, wave i=w reads
// ch 4i..4i+3), so no __syncthreads — each wave syncs only its own vmcnt.
//
// LDS [hh][ch][w] = [4][16][64] floats (16 KB, linear):
//  - fill via __builtin_amdgcn_global_load_lds width=16: dest for load hh is
//    (hh*4096 + wid*1024) [wave-uniform] + lane*16  — exactly the HW contract.
//    (lane*16 == (lane>>4)*256 + (lane&15)*16 == ch_local*256 + l16*16)
//  - read 16x ds_read_b32 at idx = q*1024 + i*256 + j*64 + w: lanes vary only
//    in w -> stride-1 -> 2-way bank alias (free).
//  - store 4x float4, each wave-instr = 1 KB contiguous.

#define AS_GLOBAL __attribute__((address_space(1)))
#define AS_LOCAL  __attribute__((address_space(3)))

__global__ __launch_bounds__(256) void recon_ps4_dma(
    const float* __restrict__ in, float* __restrict__ out)
{
    __shared__ float lds[4096];        // [4][16][64] floats = 16 KB

    const int td   = threadIdx.x;
    const int wid  = td >> 6;          // wave id = store sub-row i
    const int lane = td & 63;          // store w
    const int ch   = td >> 4;          // load channel (== wid*4 + (lane>>4))
    const int l16  = td & 15;          // load w-quad

    const int g  = blockIdx.x & 3;     // h4 group (tiles h4 = 4g .. 4g+3)
    const int bc = blockIdx.x >> 2;    // b*25 + c

    // global src element offset: (bc*16+ch)*4096 + h4*256 + hh*64 + l16*4
    const float* src0 = in + ((size_t)(bc * 16 + ch) << 12)
                           + (size_t)(g << 10) + (l16 << 2);
    // LDS byte dest base: wid*1024 + lane*16 (+ hh*4096 per load)
    char* lds_dst = (char*)lds + (wid << 10) + (lane << 4);
    // LDS read base (elements): i*256 + w
    const float* rbase = lds + (wid << 8) + lane;
    // output element base: bc*65536 + (4g)*4096
    float* dst0 = out + ((size_t)bc << 16) + ((size_t)g << 14);

    #pragma unroll
    for (int it = 0; it < 4; ++it) {
        const float* s = src0 + it * 256;

        #pragma unroll
        for (int hh = 0; hh < 4; ++hh) {
            __builtin_amdgcn_global_load_lds(
                (const AS_GLOBAL void*)(s + hh * 64),
                (AS_LOCAL void*)(lds_dst + hh * 4096),
                16, 0, 0);
        }
        // wave-local: wait only this wave's DMA (no __syncthreads)
        asm volatile("s_waitcnt vmcnt(0)" ::: "memory");

        float v[4][4];
        #pragma unroll
        for (int q = 0; q < 4; ++q)
            #pragma unroll
            for (int j = 0; j < 4; ++j)
                v[q][j] = rbase[q * 1024 + j * 64];

        // reads complete before next iteration's DMA overwrites the buffer
        asm volatile("s_waitcnt lgkmcnt(0)" ::: "memory");

        float* d = dst0 + (it << 12) + (td << 2);
        #pragma unroll
        for (int q = 0; q < 4; ++q) {
            float4 o = make_float4(v[q][0], v[q][1], v[q][2], v[q][3]);
            *reinterpret_cast<float4*>(d + (q << 10)) = o;
        }
    }
}

extern "C" void kernel_launch(void* const* d_in, const int* in_sizes, int n_in,
                              void* d_out, int out_size, void* d_ws, size_t ws_size,
                              hipStream_t stream) {
    const float* in = (const float*)d_in[0];
    float* out = (float*)d_out;

    // tiles = 32*25*16 = 12800; 4 tiles/block -> 3200 blocks
    recon_ps4_dma<<<3200, 256, 0, stream>>>(in, out);
}

// Round 5
// 66.924 us; speedup vs baseline: 1.3157x; 1.3157x over previous
//
#include <hip/hip_runtime.h>

// Pixel-shuffle r=4: out[b, c, 4h+i, 4w+j] = in[b, c*16 + i*4 + j, h, w]
// B=32, c_out=25, H=W=64, fp32. Memory-bound permute (420 MB total traffic).
//
// Block (256 thr) = one tile (b, c, h4): 16 ch x 4 input rows x 64 w.
// LDS [hh][ch][w] = [4][16][64] fp32 (16 KB, linear, no pad):
//   write: thread td -> lds[hh][td>>4][(td&15)*4 ..+3] => 4x ds_write_b128,
//          each wave-instr covers 1 KB contiguous (conflict-free).
//   read : thread td (wave i=td>>6, lane w=td&63) -> lds[q][i*4+j][w],
//          lanes stride-1 => 2-way bank alias (free, m136).
// The transpose is WAVE-LOCAL: wave wid writes ch 4*wid..4*wid+3, and read
// wave i==wid reads exactly those channels -> NO __syncthreads needed; the
// compiler's per-wave lgkmcnt waits cover the RAW hazard.
// Stores: 4x float4 per thread, each wave-instr = 1 KB contiguous output row
// segment; nontemporal (write-once stream).

typedef float vfloat4 __attribute__((ext_vector_type(4)));

__global__ __launch_bounds__(256) void recon_ps4(
    const float* __restrict__ in, float* __restrict__ out)
{
    __shared__ float lds[4096];        // [4][16][64] = 16 KB

    const int td  = threadIdx.x;
    const int wid = td >> 6;           // wave id = output sub-row i
    const int w   = td & 63;           // lane    = output w-quad index
    const int ch  = td >> 4;           // load channel (wave-local: 4*wid + ..)
    const int l16 = td & 15;           // load w-quad

    const int h4 = blockIdx.x & 15;    // input h block
    const int bc = blockIdx.x >> 4;    // b*25 + c

    // ---- global -> registers: 4x float4 ----
    // element offset: (bc*16+ch)*4096 + h4*256 + hh*64 + l16*4
    const float* src = in + ((size_t)(bc * 16 + ch) << 12) + (h4 << 8) + (l16 << 2);
    vfloat4 v[4];
    #pragma unroll
    for (int hh = 0; hh < 4; ++hh)
        v[hh] = *reinterpret_cast<const vfloat4*>(src + (hh << 6));

    // ---- registers -> LDS: 4x ds_write_b128 ----
    float* wp = lds + (ch << 6) + (l16 << 2);      // [.][ch][l16*4]
    #pragma unroll
    for (int hh = 0; hh < 4; ++hh)
        *reinterpret_cast<vfloat4*>(wp + (hh << 10)) = v[hh];

    // ---- LDS -> registers -> global (wave-local, no barrier) ----
    const float* rb = lds + (wid << 8) + w;        // [q][wid*4+j][w]
    float* dst = out + ((size_t)bc << 16) + (h4 << 12) + (wid << 8) + (w << 2);
    #pragma unroll
    for (int q = 0; q < 4; ++q) {
        vfloat4 o;
        o.x = rb[(q << 10)      ];
        o.y = rb[(q << 10) +  64];
        o.z = rb[(q << 10) + 128];
        o.w = rb[(q << 10) + 192];
        __builtin_nontemporal_store(o, reinterpret_cast<vfloat4*>(dst + (q << 10)));
    }
}

extern "C" void kernel_launch(void* const* d_in, const int* in_sizes, int n_in,
                              void* d_out, int out_size, void* d_ws, size_t ws_size,
                              hipStream_t stream) {
    const float* in = (const float*)d_in[0];
    float* out = (float*)d_out;

    // tiles = B * c_out * (H/4) = 32*25*16 = 12800 blocks
    recon_ps4<<<12800, 256, 0, stream>>>(in, out);
}